// Round 1
// baseline (2563.091 us; speedup 1.0000x reference)
//
#include <hip/hip_runtime.h>
#include <cstdint>
#include <utility>

#define BSZ   64
#define MAXQ  32
#define DH    300
#define N_ENT 100000
#define N_REL 18
#define N_TRI 600000
#define D_CLS 1024

// e_s [64][N_ENT] -> e_t [N_ENT][64]
__global__ __launch_bounds__(256) void k_transpose(const float* __restrict__ e_s,
                                                   float* __restrict__ e_t) {
  __shared__ float T[64][65];
  int e0 = blockIdx.x * 64;
  int lane = threadIdx.x & 63;
  int w = threadIdx.x >> 6;
  for (int b = w; b < 64; b += 4) {
    int e = e0 + lane;
    T[b][lane] = (e < N_ENT) ? e_s[b * N_ENT + e] : 0.f;
  }
  __syncthreads();
  for (int i = w; i < 64; i += 4) {
    int e = e0 + i;
    if (e < N_ENT) e_t[e * 64 + lane] = T[lane][i];
  }
}

// Fused per-step controller: q_t, cq_t, word attention softmax, last_c, rel_dist.
// One block per batch element.
__global__ __launch_bounds__(320) void k_step(
    const float* __restrict__ qwh, const float* __restrict__ qemb,
    const float* __restrict__ Wstep, const float* __restrict__ bstep,
    const float* __restrict__ Wcq, const float* __restrict__ bcq,
    const float* __restrict__ Wca, const float* __restrict__ bca,
    const float* __restrict__ Wrel, const float* __restrict__ brel,
    float* __restrict__ last_c, float* __restrict__ rel_dist, int t) {
  int b = blockIdx.x;
  int tid = threadIdx.x;
  __shared__ float qe[DH], qtL[DH], lcL[DH], wcq[DH];
  __shared__ float lg[MAXQ], red[MAXQ * 8], dist[MAXQ];
  __shared__ float relL[N_REL];
  __shared__ float mx, sm;

  for (int j = tid; j < DH; j += 320) {
    qe[j] = qemb[b * DH + j];
    lcL[j] = last_c[b * DH + j];
  }
  __syncthreads();

  // q_t = tanh(qe @ Wstep[t] + bstep[t])
  const float* Wt = Wstep + t * DH * DH;
  for (int j = tid; j < DH; j += 320) {
    float acc = bstep[t * DH + j];
    for (int k = 0; k < DH; k++) acc += qe[k] * Wt[k * DH + j];
    qtL[j] = tanhf(acc);
  }
  __syncthreads();

  // cq = [last_c, q_t] @ Wcq + bcq ; wcq = cq * Wca
  for (int j = tid; j < DH; j += 320) {
    float acc = bcq[j];
    for (int k = 0; k < DH; k++) acc += lcL[k] * Wcq[k * DH + j];
    for (int k = 0; k < DH; k++) acc += qtL[k] * Wcq[(DH + k) * DH + j];
    wcq[j] = acc * Wca[j];
  }
  __syncthreads();

  // q_logits[q] = sum_d wcq[d] * qwh[b,q,d] + b_ca : 8 partials per q
  if (tid < MAXQ * 8) {
    int q = tid >> 3, sub = tid & 7;
    const float* row = qwh + (b * MAXQ + q) * DH;
    float acc = 0.f;
    for (int d = sub; d < DH; d += 8) acc += wcq[d] * row[d];
    red[tid] = acc;
  }
  __syncthreads();
  if (tid < MAXQ) {
    float acc = bca[0];
    for (int s = 0; s < 8; s++) acc += red[tid * 8 + s];
    lg[tid] = acc;
  }
  __syncthreads();
  if (tid == 0) {
    float m = lg[0];
    for (int q = 1; q < MAXQ; q++) m = fmaxf(m, lg[q]);
    mx = m;
  }
  __syncthreads();
  if (tid < MAXQ) dist[tid] = expf(lg[tid] - mx);
  __syncthreads();
  if (tid == 0) {
    float s = 0.f;
    for (int q = 0; q < MAXQ; q++) s += dist[q];
    sm = s;
  }
  __syncthreads();

  // last_c[j] = sum_q softmax(q) * qwh[b,q,j]
  for (int j = tid; j < DH; j += 320) {
    float acc = 0.f;
    for (int q = 0; q < MAXQ; q++) acc += dist[q] * qwh[(b * MAXQ + q) * DH + j];
    acc /= sm;
    lcL[j] = acc;
    last_c[b * DH + j] = acc;
  }
  __syncthreads();

  // rel_dist = softmax(last_c @ Wrel + brel)
  if (tid < N_REL) {
    float acc = brel[tid];
    for (int d = 0; d < DH; d++) acc += lcL[d] * Wrel[d * N_REL + tid];
    relL[tid] = acc;
  }
  __syncthreads();
  if (tid == 0) {
    float m = relL[0];
    for (int r = 1; r < N_REL; r++) m = fmaxf(m, relL[r]);
    mx = m;
  }
  __syncthreads();
  if (tid < N_REL) relL[tid] = expf(relL[tid] - mx);
  __syncthreads();
  if (tid == 0) {
    float s = 0.f;
    for (int r = 0; r < N_REL; r++) s += relL[r];
    sm = s;
  }
  __syncthreads();
  if (tid < N_REL) rel_dist[b * N_REL + tid] = relL[tid] / sm;
}

// follow: one wave per triple, lane = batch
__global__ __launch_bounds__(256) void k_follow(
    const float* __restrict__ e_in, const float* __restrict__ rel_dist,
    const int* __restrict__ subj, const int* __restrict__ rel,
    const int* __restrict__ obj, float* __restrict__ e_out) {
  __shared__ float relL[BSZ * N_REL];
  for (int i = threadIdx.x; i < BSZ * N_REL; i += 256) relL[i] = rel_dist[i];
  __syncthreads();
  int lane = threadIdx.x & 63;
  int wave = (blockIdx.x << 2) | (threadIdx.x >> 6);
  int nwaves = gridDim.x << 2;
  for (int i = wave; i < N_TRI; i += nwaves) {
    int s = subj[i], r = rel[i], o = obj[i];
    float x = e_in[s * 64 + lane] * relL[lane * N_REL + r];
    atomicAdd(&e_out[o * 64 + lane], x);
  }
}

// per-batch sums over entities (e in [ent][b] layout)
__global__ __launch_bounds__(256) void k_sums(const float* __restrict__ e,
                                              float* __restrict__ sums) {
  __shared__ float red[4][64];
  int lane = threadIdx.x & 63;
  int w = threadIdx.x >> 6;
  int gw = blockIdx.x * 4 + w;
  int nw = gridDim.x * 4;
  float acc = 0.f;
  for (int ent = gw; ent < N_ENT; ent += nw) acc += e[ent * 64 + lane];
  red[w][lane] = acc;
  __syncthreads();
  if (threadIdx.x < 64) {
    float s = red[0][threadIdx.x] + red[1][threadIdx.x] +
              red[2][threadIdx.x] + red[3][threadIdx.x];
    atomicAdd(&sums[threadIdx.x], s);
  }
}

#define PF_NB 400
#define PF_EPB 250
#define PF_TD 16
// partials[blk][d][b] = sum over this block's entities of normed[e][b]*ent_emb[e][d]
__global__ __launch_bounds__(256) void k_predfeat(
    const float* __restrict__ e, const float* __restrict__ sums,
    const float* __restrict__ ent_emb, float* __restrict__ partials) {
  __shared__ float embL[PF_EPB * PF_TD];
  int blk = blockIdx.x;
  int e0 = blk * PF_EPB;
  int b = threadIdx.x & 63, ds = threadIdx.x >> 6;
  float inv = 1.f / (sums[b] + 1e-6f);
  float* pout = partials + blk * (DH * 64);
  for (int d0 = 0; d0 < DH; d0 += PF_TD) {
    __syncthreads();
    for (int i = threadIdx.x; i < PF_EPB * PF_TD; i += 256) {
      int ee = i / PF_TD, dd = i % PF_TD;
      int d = d0 + dd;
      embL[i] = (d < DH) ? ent_emb[(e0 + ee) * DH + d] : 0.f;
    }
    __syncthreads();
    float a0 = 0.f, a1 = 0.f, a2 = 0.f, a3 = 0.f;
    #pragma unroll 4
    for (int ee = 0; ee < PF_EPB; ee++) {
      float ev = e[(e0 + ee) * 64 + b];
      const float* em = &embL[ee * PF_TD + ds * 4];
      a0 += ev * em[0];
      a1 += ev * em[1];
      a2 += ev * em[2];
      a3 += ev * em[3];
    }
    int dbase = d0 + ds * 4;
    if (dbase + 0 < DH) pout[(dbase + 0) * 64 + b] = a0 * inv;
    if (dbase + 1 < DH) pout[(dbase + 1) * 64 + b] = a1 * inv;
    if (dbase + 2 < DH) pout[(dbase + 2) * 64 + b] = a2 * inv;
    if (dbase + 3 < DH) pout[(dbase + 3) * 64 + b] = a3 * inv;
  }
}

// pf[b][d] = sum_blk partials[blk][d][b]
__global__ __launch_bounds__(256) void k_reduce_pf(const float* __restrict__ partials,
                                                   float* __restrict__ pf) {
  int j = blockIdx.x * 256 + threadIdx.x;
  if (j >= DH * 64) return;
  float acc = 0.f;
  for (int c = 0; c < PF_NB; c++) acc += partials[c * (DH * 64) + j];
  int d = j >> 6, b = j & 63;
  pf[b * DH + d] = acc;
}

// hiddenT[j][b] = relu(pf[b,:] @ We1[:,j] + be1[j])   (transposed store)
__global__ __launch_bounds__(256) void k_hidden(const float* __restrict__ pf,
                                                const float* __restrict__ We1,
                                                const float* __restrict__ be1,
                                                float* __restrict__ hiddenT) {
  int idx = blockIdx.x * 256 + threadIdx.x;
  int j = idx & (D_CLS - 1);
  int b = idx >> 10;
  float acc = be1[j];
  const float* p = pf + b * DH;
  for (int k = 0; k < DH; k++) acc += p[k] * We1[k * D_CLS + j];
  hiddenT[j * 64 + b] = fmaxf(acc, 0.f);
}

// out[b][o] = hiddenT[:,b] . We2[:,o] + be2[o].  hT access is wave-uniform (s_load).
__global__ __launch_bounds__(256) void k_final(const float* __restrict__ hT,
                                               const float* __restrict__ We2,
                                               const float* __restrict__ be2,
                                               float* __restrict__ out) {
  int o = blockIdx.x * 256 + threadIdx.x;
  bool valid = (o < N_ENT);
  int oc = valid ? o : 0;
  float acc[64];
  #pragma unroll
  for (int b = 0; b < 64; b++) acc[b] = 0.f;
  for (int k = 0; k < D_CLS; k++) {
    float w = We2[k * N_ENT + oc];
    const float* h = hT + k * 64;
    #pragma unroll
    for (int b = 0; b < 64; b++) acc[b] += h[b] * w;
  }
  if (valid) {
    float bias = be2[o];
    #pragma unroll
    for (int b = 0; b < 64; b++) out[b * N_ENT + o] = acc[b] + bias;
  }
}

extern "C" void kernel_launch(void* const* d_in, const int* in_sizes, int n_in,
                              void* d_out, int out_size, void* d_ws, size_t ws_size,
                              hipStream_t stream) {
  const float* qwh   = (const float*)d_in[0];
  const float* qemb  = (const float*)d_in[1];
  const float* e_s   = (const float*)d_in[2];
  const float* Wstep = (const float*)d_in[3];
  const float* bstep = (const float*)d_in[4];
  const float* Wcq   = (const float*)d_in[5];
  const float* bcq   = (const float*)d_in[6];
  const float* Wca   = (const float*)d_in[7];
  const float* bca   = (const float*)d_in[8];
  const float* Wrel  = (const float*)d_in[9];
  const float* brel  = (const float*)d_in[10];
  const float* eemb  = (const float*)d_in[11];
  const float* We1   = (const float*)d_in[12];
  const float* be1   = (const float*)d_in[13];
  const float* We2   = (const float*)d_in[14];
  const float* be2   = (const float*)d_in[15];
  const int* subj    = (const int*)d_in[16];
  const int* rel     = (const int*)d_in[17];
  const int* obj     = (const int*)d_in[18];
  float* out = (float*)d_out;

  float* ws = (float*)d_ws;
  float* e_a      = ws;                       // 6,400,000
  float* e_b      = e_a + (size_t)N_ENT * 64; // 6,400,000
  float* last_c   = e_b + (size_t)N_ENT * 64; // 19,200
  float* rel_d    = last_c + BSZ * DH;        // 1,152
  float* sums     = rel_d + BSZ * N_REL;      // 64
  float* pf       = sums + 64;                // 19,200
  float* hiddenT  = pf + BSZ * DH;            // 65,536
  float* partials = hiddenT + BSZ * D_CLS;    // 400*19,200 = 7,680,000

  // zero last_c (+rel_d scratch) and sums in one contiguous memset
  hipMemsetAsync(last_c, 0, (size_t)(BSZ * DH + BSZ * N_REL + 64) * sizeof(float), stream);

  k_transpose<<<(N_ENT + 63) / 64, 256, 0, stream>>>(e_s, e_a);

  float* cur = e_a;
  float* nxt = e_b;
  for (int t = 0; t < 3; t++) {
    k_step<<<BSZ, 320, 0, stream>>>(qwh, qemb, Wstep, bstep, Wcq, bcq, Wca, bca,
                                    Wrel, brel, last_c, rel_d, t);
    hipMemsetAsync(nxt, 0, (size_t)N_ENT * 64 * sizeof(float), stream);
    k_follow<<<2048, 256, 0, stream>>>(cur, rel_d, subj, rel, obj, nxt);
    std::swap(cur, nxt);
  }

  k_sums<<<256, 256, 0, stream>>>(cur, sums);
  k_predfeat<<<PF_NB, 256, 0, stream>>>(cur, sums, eemb, partials);
  k_reduce_pf<<<(DH * 64 + 255) / 256, 256, 0, stream>>>(partials, pf);
  k_hidden<<<(BSZ * D_CLS) / 256, 256, 0, stream>>>(pf, We1, be1, hiddenT);
  k_final<<<(N_ENT + 255) / 256, 256, 0, stream>>>(hiddenT, We2, be2, out);
}

// Round 2
// 1974.476 us; speedup vs baseline: 1.2981x; 1.2981x over previous
//
#include <hip/hip_runtime.h>
#include <cstdint>
#include <utility>

#define BSZ   64
#define MAXQ  32
#define DH    300
#define N_ENT 100000
#define N_REL 18
#define N_TRI 600000
#define D_CLS 1024

// e_s [64][N_ENT] -> e_t [N_ENT][64]
__global__ __launch_bounds__(256) void k_transpose(const float* __restrict__ e_s,
                                                   float* __restrict__ e_t) {
  __shared__ float T[64][65];
  int e0 = blockIdx.x * 64;
  int lane = threadIdx.x & 63;
  int w = threadIdx.x >> 6;
  for (int b = w; b < 64; b += 4) {
    int e = e0 + lane;
    T[b][lane] = (e < N_ENT) ? e_s[b * N_ENT + e] : 0.f;
  }
  __syncthreads();
  for (int i = w; i < 64; i += 4) {
    int e = e0 + i;
    if (e < N_ENT) e_t[e * 64 + lane] = T[lane][i];
  }
}

// Fused per-step controller: q_t, cq_t, word attention softmax, last_c, rel_dist.
__global__ __launch_bounds__(320) void k_step(
    const float* __restrict__ qwh, const float* __restrict__ qemb,
    const float* __restrict__ Wstep, const float* __restrict__ bstep,
    const float* __restrict__ Wcq, const float* __restrict__ bcq,
    const float* __restrict__ Wca, const float* __restrict__ bca,
    const float* __restrict__ Wrel, const float* __restrict__ brel,
    float* __restrict__ last_c, float* __restrict__ rel_dist, int t) {
  int b = blockIdx.x;
  int tid = threadIdx.x;
  __shared__ float qe[DH], qtL[DH], lcL[DH], wcq[DH];
  __shared__ float lg[MAXQ], red[MAXQ * 8], dist[MAXQ];
  __shared__ float relL[N_REL];
  __shared__ float mx, sm;

  for (int j = tid; j < DH; j += 320) {
    qe[j] = qemb[b * DH + j];
    lcL[j] = last_c[b * DH + j];
  }
  __syncthreads();

  const float* Wt = Wstep + t * DH * DH;
  for (int j = tid; j < DH; j += 320) {
    float acc = bstep[t * DH + j];
    for (int k = 0; k < DH; k++) acc += qe[k] * Wt[k * DH + j];
    qtL[j] = tanhf(acc);
  }
  __syncthreads();

  for (int j = tid; j < DH; j += 320) {
    float acc = bcq[j];
    for (int k = 0; k < DH; k++) acc += lcL[k] * Wcq[k * DH + j];
    for (int k = 0; k < DH; k++) acc += qtL[k] * Wcq[(DH + k) * DH + j];
    wcq[j] = acc * Wca[j];
  }
  __syncthreads();

  if (tid < MAXQ * 8) {
    int q = tid >> 3, sub = tid & 7;
    const float* row = qwh + (b * MAXQ + q) * DH;
    float acc = 0.f;
    for (int d = sub; d < DH; d += 8) acc += wcq[d] * row[d];
    red[tid] = acc;
  }
  __syncthreads();
  if (tid < MAXQ) {
    float acc = bca[0];
    for (int s = 0; s < 8; s++) acc += red[tid * 8 + s];
    lg[tid] = acc;
  }
  __syncthreads();
  if (tid == 0) {
    float m = lg[0];
    for (int q = 1; q < MAXQ; q++) m = fmaxf(m, lg[q]);
    mx = m;
  }
  __syncthreads();
  if (tid < MAXQ) dist[tid] = expf(lg[tid] - mx);
  __syncthreads();
  if (tid == 0) {
    float s = 0.f;
    for (int q = 0; q < MAXQ; q++) s += dist[q];
    sm = s;
  }
  __syncthreads();

  for (int j = tid; j < DH; j += 320) {
    float acc = 0.f;
    for (int q = 0; q < MAXQ; q++) acc += dist[q] * qwh[(b * MAXQ + q) * DH + j];
    acc /= sm;
    lcL[j] = acc;
    last_c[b * DH + j] = acc;
  }
  __syncthreads();

  if (tid < N_REL) {
    float acc = brel[tid];
    for (int d = 0; d < DH; d++) acc += lcL[d] * Wrel[d * N_REL + tid];
    relL[tid] = acc;
  }
  __syncthreads();
  if (tid == 0) {
    float m = relL[0];
    for (int r = 1; r < N_REL; r++) m = fmaxf(m, relL[r]);
    mx = m;
  }
  __syncthreads();
  if (tid < N_REL) relL[tid] = expf(relL[tid] - mx);
  __syncthreads();
  if (tid == 0) {
    float s = 0.f;
    for (int r = 0; r < N_REL; r++) s += relL[r];
    sm = s;
  }
  __syncthreads();
  if (tid < N_REL) rel_dist[b * N_REL + tid] = relL[tid] / sm;
}

// follow: one wave per triple, lane = batch
__global__ __launch_bounds__(256) void k_follow(
    const float* __restrict__ e_in, const float* __restrict__ rel_dist,
    const int* __restrict__ subj, const int* __restrict__ rel,
    const int* __restrict__ obj, float* __restrict__ e_out) {
  __shared__ float relL[BSZ * N_REL];
  for (int i = threadIdx.x; i < BSZ * N_REL; i += 256) relL[i] = rel_dist[i];
  __syncthreads();
  int lane = threadIdx.x & 63;
  int wave = (blockIdx.x << 2) | (threadIdx.x >> 6);
  int nwaves = gridDim.x << 2;
  for (int i = wave; i < N_TRI; i += nwaves) {
    int s = subj[i], r = rel[i], o = obj[i];
    float x = e_in[s * 64 + lane] * relL[lane * N_REL + r];
    atomicAdd(&e_out[o * 64 + lane], x);
  }
}

__global__ __launch_bounds__(256) void k_sums(const float* __restrict__ e,
                                              float* __restrict__ sums) {
  __shared__ float red[4][64];
  int lane = threadIdx.x & 63;
  int w = threadIdx.x >> 6;
  int gw = blockIdx.x * 4 + w;
  int nw = gridDim.x * 4;
  float acc = 0.f;
  for (int ent = gw; ent < N_ENT; ent += nw) acc += e[ent * 64 + lane];
  red[w][lane] = acc;
  __syncthreads();
  if (threadIdx.x < 64) {
    float s = red[0][threadIdx.x] + red[1][threadIdx.x] +
              red[2][threadIdx.x] + red[3][threadIdx.x];
    atomicAdd(&sums[threadIdx.x], s);
  }
}

#define PF_NB 400
#define PF_EPB 250
#define PF_CH 32
#define PF_RS 304   // padded row stride (floats), 76 float4
// partials[blk][d(304)][b] = sum over block's entities of normed[e][b]*emb[e][d]
// thread (b = tid&63, g = tid>>6) accumulates d = g*76 .. g*76+75 in 19 float4.
__global__ __launch_bounds__(256) void k_predfeat(
    const float* __restrict__ e, const float* __restrict__ sums,
    const float* __restrict__ ent_emb, float* __restrict__ partials) {
  __shared__ float embL[PF_CH * PF_RS];   // 38,912 B
  __shared__ float eL[PF_CH * 64];        //  8,192 B
  int tid = threadIdx.x;
  int b = tid & 63, g = tid >> 6;
  int e0 = blockIdx.x * PF_EPB;
  int e1 = e0 + PF_EPB;

  // per-thread inverse-norm for the 4 b's this thread stages (base = (4*tid)&63)
  int sb = (4 * tid) & 63;
  float4 inv4 = make_float4(1.f / (sums[sb + 0] + 1e-6f), 1.f / (sums[sb + 1] + 1e-6f),
                            1.f / (sums[sb + 2] + 1e-6f), 1.f / (sums[sb + 3] + 1e-6f));

  float4 acc[19];
  #pragma unroll
  for (int k = 0; k < 19; k++) acc[k] = make_float4(0.f, 0.f, 0.f, 0.f);

  float4* embL4 = (float4*)embL;
  float4* eL4 = (float4*)eL;

  for (int ecur = e0; ecur < e1; ecur += PF_CH) {
    int n = min(PF_CH, e1 - ecur);
    __syncthreads();
    // stage emb rows (75 float4 each) into padded rows of 76 float4; zero pad
    const float4* src = (const float4*)(ent_emb + (size_t)ecur * DH);
    for (int i = tid; i < n * 75; i += 256) {
      int ee = i / 75, j = i - ee * 75;
      embL4[ee * 76 + j] = src[i];
      if (j == 0) embL4[ee * 76 + 75] = make_float4(0.f, 0.f, 0.f, 0.f);
    }
    // stage e chunk, normalized
    const float4* esrc = (const float4*)(e + (size_t)ecur * 64);
    for (int i = tid; i < n * 16; i += 256) {
      float4 v = esrc[i];
      v.x *= inv4.x; v.y *= inv4.y; v.z *= inv4.z; v.w *= inv4.w;
      eL4[i] = v;
    }
    __syncthreads();
    for (int ee = 0; ee < n; ee++) {
      float ev = eL[ee * 64 + b];
      const float4* em = embL4 + ee * 76 + g * 19;
      #pragma unroll
      for (int k = 0; k < 19; k++) {
        float4 m = em[k];
        acc[k].x += ev * m.x;
        acc[k].y += ev * m.y;
        acc[k].z += ev * m.z;
        acc[k].w += ev * m.w;
      }
    }
  }

  float* pout = partials + (size_t)blockIdx.x * (PF_RS * 64);
  #pragma unroll
  for (int k = 0; k < 19; k++) {
    int d = g * 76 + k * 4;
    pout[(d + 0) * 64 + b] = acc[k].x;
    pout[(d + 1) * 64 + b] = acc[k].y;
    pout[(d + 2) * 64 + b] = acc[k].z;
    pout[(d + 3) * 64 + b] = acc[k].w;
  }
}

// pf[b][d] = sum_blk partials[blk][d][b]   (d < 300 only)
__global__ __launch_bounds__(256) void k_reduce_pf(const float* __restrict__ partials,
                                                   float* __restrict__ pf) {
  int j = blockIdx.x * 256 + threadIdx.x;
  if (j >= DH * 64) return;
  int d = j >> 6, b = j & 63;
  float acc = 0.f;
  for (int c = 0; c < PF_NB; c++) acc += partials[(size_t)c * (PF_RS * 64) + j];
  pf[b * DH + d] = acc;
}

// hiddenT[j][b] = relu(pf[b,:] @ We1[:,j] + be1[j])
__global__ __launch_bounds__(256) void k_hidden(const float* __restrict__ pf,
                                                const float* __restrict__ We1,
                                                const float* __restrict__ be1,
                                                float* __restrict__ hiddenT) {
  int idx = blockIdx.x * 256 + threadIdx.x;
  int j = idx & (D_CLS - 1);
  int b = idx >> 10;
  float acc = be1[j];
  const float* p = pf + b * DH;
  for (int k = 0; k < DH; k++) acc += p[k] * We1[k * D_CLS + j];
  hiddenT[j * 64 + b] = fmaxf(acc, 0.f);
}

// out[b][o] = hT[:,b] . We2[:,o] + be2[o], hT staged in LDS 128-k chunks.
#define KF_KC 128
__global__ __launch_bounds__(256) void k_final(const float* __restrict__ hT,
                                               const float* __restrict__ We2,
                                               const float* __restrict__ be2,
                                               float* __restrict__ out) {
  __shared__ float hL[KF_KC * 64];   // 32 KB
  int tid = threadIdx.x;
  int o = blockIdx.x * 256 + tid;
  bool valid = (o < N_ENT);
  int oc = valid ? o : 0;
  float4 acc[16];
  #pragma unroll
  for (int i = 0; i < 16; i++) acc[i] = make_float4(0.f, 0.f, 0.f, 0.f);
  float4* hL4 = (float4*)hL;

  for (int k0 = 0; k0 < D_CLS; k0 += KF_KC) {
    __syncthreads();
    const float4* src = (const float4*)(hT + (size_t)k0 * 64);
    #pragma unroll
    for (int i = 0; i < (KF_KC * 64 / 4) / 256; i++)
      hL4[tid + i * 256] = src[tid + i * 256];
    __syncthreads();
    for (int k = 0; k < KF_KC; k++) {
      float w = We2[(size_t)(k0 + k) * N_ENT + oc];
      const float4* h = hL4 + k * 16;
      #pragma unroll
      for (int i = 0; i < 16; i++) {
        float4 hv = h[i];
        acc[i].x += hv.x * w;
        acc[i].y += hv.y * w;
        acc[i].z += hv.z * w;
        acc[i].w += hv.w * w;
      }
    }
  }
  if (valid) {
    float bias = be2[o];
    #pragma unroll
    for (int i = 0; i < 16; i++) {
      out[(size_t)(i * 4 + 0) * N_ENT + o] = acc[i].x + bias;
      out[(size_t)(i * 4 + 1) * N_ENT + o] = acc[i].y + bias;
      out[(size_t)(i * 4 + 2) * N_ENT + o] = acc[i].z + bias;
      out[(size_t)(i * 4 + 3) * N_ENT + o] = acc[i].w + bias;
    }
  }
}

extern "C" void kernel_launch(void* const* d_in, const int* in_sizes, int n_in,
                              void* d_out, int out_size, void* d_ws, size_t ws_size,
                              hipStream_t stream) {
  const float* qwh   = (const float*)d_in[0];
  const float* qemb  = (const float*)d_in[1];
  const float* e_s   = (const float*)d_in[2];
  const float* Wstep = (const float*)d_in[3];
  const float* bstep = (const float*)d_in[4];
  const float* Wcq   = (const float*)d_in[5];
  const float* bcq   = (const float*)d_in[6];
  const float* Wca   = (const float*)d_in[7];
  const float* bca   = (const float*)d_in[8];
  const float* Wrel  = (const float*)d_in[9];
  const float* brel  = (const float*)d_in[10];
  const float* eemb  = (const float*)d_in[11];
  const float* We1   = (const float*)d_in[12];
  const float* be1   = (const float*)d_in[13];
  const float* We2   = (const float*)d_in[14];
  const float* be2   = (const float*)d_in[15];
  const int* subj    = (const int*)d_in[16];
  const int* rel     = (const int*)d_in[17];
  const int* obj     = (const int*)d_in[18];
  float* out = (float*)d_out;

  float* ws = (float*)d_ws;
  float* e_a      = ws;                       // 6,400,000
  float* e_b      = e_a + (size_t)N_ENT * 64; // 6,400,000
  float* last_c   = e_b + (size_t)N_ENT * 64; // 19,200
  float* rel_d    = last_c + BSZ * DH;        // 1,152
  float* sums     = rel_d + BSZ * N_REL;      // 64
  float* pf       = sums + 64;                // 19,200
  float* hiddenT  = pf + BSZ * DH;            // 65,536
  float* partials = hiddenT + BSZ * D_CLS;    // 400*304*64 = 7,782,400

  hipMemsetAsync(last_c, 0, (size_t)(BSZ * DH + BSZ * N_REL + 64) * sizeof(float), stream);

  k_transpose<<<(N_ENT + 63) / 64, 256, 0, stream>>>(e_s, e_a);

  float* cur = e_a;
  float* nxt = e_b;
  for (int t = 0; t < 3; t++) {
    k_step<<<BSZ, 320, 0, stream>>>(qwh, qemb, Wstep, bstep, Wcq, bcq, Wca, bca,
                                    Wrel, brel, last_c, rel_d, t);
    hipMemsetAsync(nxt, 0, (size_t)N_ENT * 64 * sizeof(float), stream);
    k_follow<<<2048, 256, 0, stream>>>(cur, rel_d, subj, rel, obj, nxt);
    std::swap(cur, nxt);
  }

  k_sums<<<256, 256, 0, stream>>>(cur, sums);
  k_predfeat<<<PF_NB, 256, 0, stream>>>(cur, sums, eemb, partials);
  k_reduce_pf<<<(DH * 64 + 255) / 256, 256, 0, stream>>>(partials, pf);
  k_hidden<<<(BSZ * D_CLS) / 256, 256, 0, stream>>>(pf, We1, be1, hiddenT);
  k_final<<<(N_ENT + 255) / 256, 256, 0, stream>>>(hiddenT, We2, be2, out);
}

// Round 3
// 1585.851 us; speedup vs baseline: 1.6162x; 1.2451x over previous
//
#include <hip/hip_runtime.h>
#include <cstdint>
#include <utility>

#define BSZ   64
#define MAXQ  32
#define DH    300
#define N_ENT 100000
#define N_REL 18
#define N_TRI 600000
#define D_CLS 1024

// e_s [64][N_ENT] -> e_t [N_ENT][64]
__global__ __launch_bounds__(256) void k_transpose(const float* __restrict__ e_s,
                                                   float* __restrict__ e_t) {
  __shared__ float T[64][65];
  int e0 = blockIdx.x * 64;
  int lane = threadIdx.x & 63;
  int w = threadIdx.x >> 6;
  for (int b = w; b < 64; b += 4) {
    int e = e0 + lane;
    T[b][lane] = (e < N_ENT) ? e_s[b * N_ENT + e] : 0.f;
  }
  __syncthreads();
  for (int i = w; i < 64; i += 4) {
    int e = e0 + i;
    if (e < N_ENT) e_t[e * 64 + lane] = T[lane][i];
  }
}

// Fused per-step controller: q_t, cq_t, word attention softmax, last_c, rel_dist.
__global__ __launch_bounds__(320) void k_step(
    const float* __restrict__ qwh, const float* __restrict__ qemb,
    const float* __restrict__ Wstep, const float* __restrict__ bstep,
    const float* __restrict__ Wcq, const float* __restrict__ bcq,
    const float* __restrict__ Wca, const float* __restrict__ bca,
    const float* __restrict__ Wrel, const float* __restrict__ brel,
    float* __restrict__ last_c, float* __restrict__ rel_dist, int t) {
  int b = blockIdx.x;
  int tid = threadIdx.x;
  __shared__ float qe[DH], qtL[DH], lcL[DH], wcq[DH];
  __shared__ float lg[MAXQ], red[MAXQ * 8], dist[MAXQ];
  __shared__ float relL[N_REL];
  __shared__ float mx, sm;

  for (int j = tid; j < DH; j += 320) {
    qe[j] = qemb[b * DH + j];
    lcL[j] = last_c[b * DH + j];
  }
  __syncthreads();

  const float* Wt = Wstep + t * DH * DH;
  for (int j = tid; j < DH; j += 320) {
    float acc = bstep[t * DH + j];
    for (int k = 0; k < DH; k++) acc += qe[k] * Wt[k * DH + j];
    qtL[j] = tanhf(acc);
  }
  __syncthreads();

  for (int j = tid; j < DH; j += 320) {
    float acc = bcq[j];
    for (int k = 0; k < DH; k++) acc += lcL[k] * Wcq[k * DH + j];
    for (int k = 0; k < DH; k++) acc += qtL[k] * Wcq[(DH + k) * DH + j];
    wcq[j] = acc * Wca[j];
  }
  __syncthreads();

  if (tid < MAXQ * 8) {
    int q = tid >> 3, sub = tid & 7;
    const float* row = qwh + (b * MAXQ + q) * DH;
    float acc = 0.f;
    for (int d = sub; d < DH; d += 8) acc += wcq[d] * row[d];
    red[tid] = acc;
  }
  __syncthreads();
  if (tid < MAXQ) {
    float acc = bca[0];
    for (int s = 0; s < 8; s++) acc += red[tid * 8 + s];
    lg[tid] = acc;
  }
  __syncthreads();
  if (tid == 0) {
    float m = lg[0];
    for (int q = 1; q < MAXQ; q++) m = fmaxf(m, lg[q]);
    mx = m;
  }
  __syncthreads();
  if (tid < MAXQ) dist[tid] = expf(lg[tid] - mx);
  __syncthreads();
  if (tid == 0) {
    float s = 0.f;
    for (int q = 0; q < MAXQ; q++) s += dist[q];
    sm = s;
  }
  __syncthreads();

  for (int j = tid; j < DH; j += 320) {
    float acc = 0.f;
    for (int q = 0; q < MAXQ; q++) acc += dist[q] * qwh[(b * MAXQ + q) * DH + j];
    acc /= sm;
    lcL[j] = acc;
    last_c[b * DH + j] = acc;
  }
  __syncthreads();

  if (tid < N_REL) {
    float acc = brel[tid];
    for (int d = 0; d < DH; d++) acc += lcL[d] * Wrel[d * N_REL + tid];
    relL[tid] = acc;
  }
  __syncthreads();
  if (tid == 0) {
    float m = relL[0];
    for (int r = 1; r < N_REL; r++) m = fmaxf(m, relL[r]);
    mx = m;
  }
  __syncthreads();
  if (tid < N_REL) relL[tid] = expf(relL[tid] - mx);
  __syncthreads();
  if (tid == 0) {
    float s = 0.f;
    for (int r = 0; r < N_REL; r++) s += relL[r];
    sm = s;
  }
  __syncthreads();
  if (tid < N_REL) rel_dist[b * N_REL + tid] = relL[tid] / sm;
}

// follow: one wave per triple, lane = batch
__global__ __launch_bounds__(256) void k_follow(
    const float* __restrict__ e_in, const float* __restrict__ rel_dist,
    const int* __restrict__ subj, const int* __restrict__ rel,
    const int* __restrict__ obj, float* __restrict__ e_out) {
  __shared__ float relL[BSZ * N_REL];
  for (int i = threadIdx.x; i < BSZ * N_REL; i += 256) relL[i] = rel_dist[i];
  __syncthreads();
  int lane = threadIdx.x & 63;
  int wave = (blockIdx.x << 2) | (threadIdx.x >> 6);
  int nwaves = gridDim.x << 2;
  for (int i = wave; i < N_TRI; i += nwaves) {
    int s = subj[i], r = rel[i], o = obj[i];
    float x = e_in[s * 64 + lane] * relL[lane * N_REL + r];
    atomicAdd(&e_out[o * 64 + lane], x);
  }
}

__global__ __launch_bounds__(256) void k_sums(const float* __restrict__ e,
                                              float* __restrict__ sums) {
  __shared__ float red[4][64];
  int lane = threadIdx.x & 63;
  int w = threadIdx.x >> 6;
  int gw = blockIdx.x * 4 + w;
  int nw = gridDim.x * 4;
  float acc = 0.f;
  for (int ent = gw; ent < N_ENT; ent += nw) acc += e[ent * 64 + lane];
  red[w][lane] = acc;
  __syncthreads();
  if (threadIdx.x < 64) {
    float s = red[0][threadIdx.x] + red[1][threadIdx.x] +
              red[2][threadIdx.x] + red[3][threadIdx.x];
    atomicAdd(&sums[threadIdx.x], s);
  }
}

#define PF_NB 400
#define PF_EPB 250
#define PF_CH 32
#define PF_RS 304   // padded row stride (floats), 76 float4
__global__ __launch_bounds__(256) void k_predfeat(
    const float* __restrict__ e, const float* __restrict__ sums,
    const float* __restrict__ ent_emb, float* __restrict__ partials) {
  __shared__ float embL[PF_CH * PF_RS];
  __shared__ float eL[PF_CH * 64];
  int tid = threadIdx.x;
  int b = tid & 63, g = tid >> 6;
  int e0 = blockIdx.x * PF_EPB;
  int e1 = e0 + PF_EPB;

  int sb = (4 * tid) & 63;
  float4 inv4 = make_float4(1.f / (sums[sb + 0] + 1e-6f), 1.f / (sums[sb + 1] + 1e-6f),
                            1.f / (sums[sb + 2] + 1e-6f), 1.f / (sums[sb + 3] + 1e-6f));

  float4 acc[19];
  #pragma unroll
  for (int k = 0; k < 19; k++) acc[k] = make_float4(0.f, 0.f, 0.f, 0.f);

  float4* embL4 = (float4*)embL;
  float4* eL4 = (float4*)eL;

  for (int ecur = e0; ecur < e1; ecur += PF_CH) {
    int n = min(PF_CH, e1 - ecur);
    __syncthreads();
    const float4* src = (const float4*)(ent_emb + (size_t)ecur * DH);
    for (int i = tid; i < n * 75; i += 256) {
      int ee = i / 75, j = i - ee * 75;
      embL4[ee * 76 + j] = src[i];
      if (j == 0) embL4[ee * 76 + 75] = make_float4(0.f, 0.f, 0.f, 0.f);
    }
    const float4* esrc = (const float4*)(e + (size_t)ecur * 64);
    for (int i = tid; i < n * 16; i += 256) {
      float4 v = esrc[i];
      v.x *= inv4.x; v.y *= inv4.y; v.z *= inv4.z; v.w *= inv4.w;
      eL4[i] = v;
    }
    __syncthreads();
    for (int ee = 0; ee < n; ee++) {
      float ev = eL[ee * 64 + b];
      const float4* em = embL4 + ee * 76 + g * 19;
      #pragma unroll
      for (int k = 0; k < 19; k++) {
        float4 m = em[k];
        acc[k].x += ev * m.x;
        acc[k].y += ev * m.y;
        acc[k].z += ev * m.z;
        acc[k].w += ev * m.w;
      }
    }
  }

  float* pout = partials + (size_t)blockIdx.x * (PF_RS * 64);
  #pragma unroll
  for (int k = 0; k < 19; k++) {
    int d = g * 76 + k * 4;
    pout[(d + 0) * 64 + b] = acc[k].x;
    pout[(d + 1) * 64 + b] = acc[k].y;
    pout[(d + 2) * 64 + b] = acc[k].z;
    pout[(d + 3) * 64 + b] = acc[k].w;
  }
}

__global__ __launch_bounds__(256) void k_reduce_pf(const float* __restrict__ partials,
                                                   float* __restrict__ pf) {
  int j = blockIdx.x * 256 + threadIdx.x;
  if (j >= DH * 64) return;
  int d = j >> 6, b = j & 63;
  float acc = 0.f;
  for (int c = 0; c < PF_NB; c++) acc += partials[(size_t)c * (PF_RS * 64) + j];
  pf[b * DH + d] = acc;
}

// hiddenT[j][b] = relu(pf[b,:] @ We1[:,j] + be1[j])
__global__ __launch_bounds__(256) void k_hidden(const float* __restrict__ pf,
                                                const float* __restrict__ We1,
                                                const float* __restrict__ be1,
                                                float* __restrict__ hiddenT) {
  int idx = blockIdx.x * 256 + threadIdx.x;
  int j = idx & (D_CLS - 1);
  int b = idx >> 10;
  float acc = be1[j];
  const float* p = pf + b * DH;
  for (int k = 0; k < DH; k++) acc += p[k] * We1[k * D_CLS + j];
  hiddenT[j * 64 + b] = fmaxf(acc, 0.f);
}

// out[b][o] = be2[o] for all b  (pre-init for the atomic split-K final GEMM)
__global__ __launch_bounds__(256) void k_init_out(const float* __restrict__ be2,
                                                  float* __restrict__ out) {
  int idx4 = blockIdx.x * 256 + threadIdx.x;      // float4 index
  int elem = idx4 * 4;                            // element index
  if (elem >= BSZ * N_ENT) return;
  int o = elem % N_ENT;                           // multiple of 4 (N_ENT%4==0)
  float4 bv = *(const float4*)(be2 + o);
  ((float4*)out)[idx4] = bv;
}

// Split-K final GEMM: chunk c covers k in [c*256, c*256+256).
// h values are wave-uniform (s_load broadcast); no LDS. atomicAdd into out.
#define KF_SPLIT 4
#define KF_KC (D_CLS / KF_SPLIT)
__global__ __launch_bounds__(256) void k_final(const float* __restrict__ hT,
                                               const float* __restrict__ We2,
                                               float* __restrict__ out) {
  int tid = threadIdx.x;
  int o = blockIdx.x * 256 + tid;
  bool valid = (o < N_ENT);
  int oc = valid ? o : 0;
  int k0 = blockIdx.y * KF_KC;

  float acc[64];
  #pragma unroll
  for (int b = 0; b < 64; b++) acc[b] = 0.f;

  const float* h = hT + (size_t)k0 * 64;
  const float* w = We2 + (size_t)k0 * N_ENT + oc;
  #pragma unroll 2
  for (int k = 0; k < KF_KC; k++) {
    float wv = w[(size_t)k * N_ENT];
    const float* hk = h + k * 64;
    #pragma unroll
    for (int b = 0; b < 64; b++) acc[b] += hk[b] * wv;
  }

  if (valid) {
    #pragma unroll
    for (int b = 0; b < 64; b++)
      atomicAdd(&out[(size_t)b * N_ENT + o], acc[b]);
  }
}

extern "C" void kernel_launch(void* const* d_in, const int* in_sizes, int n_in,
                              void* d_out, int out_size, void* d_ws, size_t ws_size,
                              hipStream_t stream) {
  const float* qwh   = (const float*)d_in[0];
  const float* qemb  = (const float*)d_in[1];
  const float* e_s   = (const float*)d_in[2];
  const float* Wstep = (const float*)d_in[3];
  const float* bstep = (const float*)d_in[4];
  const float* Wcq   = (const float*)d_in[5];
  const float* bcq   = (const float*)d_in[6];
  const float* Wca   = (const float*)d_in[7];
  const float* bca   = (const float*)d_in[8];
  const float* Wrel  = (const float*)d_in[9];
  const float* brel  = (const float*)d_in[10];
  const float* eemb  = (const float*)d_in[11];
  const float* We1   = (const float*)d_in[12];
  const float* be1   = (const float*)d_in[13];
  const float* We2   = (const float*)d_in[14];
  const float* be2   = (const float*)d_in[15];
  const int* subj    = (const int*)d_in[16];
  const int* rel     = (const int*)d_in[17];
  const int* obj     = (const int*)d_in[18];
  float* out = (float*)d_out;

  float* ws = (float*)d_ws;
  float* e_a      = ws;                       // 6,400,000
  float* e_b      = e_a + (size_t)N_ENT * 64; // 6,400,000
  float* last_c   = e_b + (size_t)N_ENT * 64; // 19,200
  float* rel_d    = last_c + BSZ * DH;        // 1,152
  float* sums     = rel_d + BSZ * N_REL;      // 64
  float* pf       = sums + 64;                // 19,200
  float* hiddenT  = pf + BSZ * DH;            // 65,536
  float* partials = hiddenT + BSZ * D_CLS;    // 400*304*64 = 7,782,400

  hipMemsetAsync(last_c, 0, (size_t)(BSZ * DH + BSZ * N_REL + 64) * sizeof(float), stream);

  k_transpose<<<(N_ENT + 63) / 64, 256, 0, stream>>>(e_s, e_a);

  float* cur = e_a;
  float* nxt = e_b;
  for (int t = 0; t < 3; t++) {
    k_step<<<BSZ, 320, 0, stream>>>(qwh, qemb, Wstep, bstep, Wcq, bcq, Wca, bca,
                                    Wrel, brel, last_c, rel_d, t);
    hipMemsetAsync(nxt, 0, (size_t)N_ENT * 64 * sizeof(float), stream);
    k_follow<<<2048, 256, 0, stream>>>(cur, rel_d, subj, rel, obj, nxt);
    std::swap(cur, nxt);
  }

  k_sums<<<256, 256, 0, stream>>>(cur, sums);
  k_predfeat<<<PF_NB, 256, 0, stream>>>(cur, sums, eemb, partials);
  k_reduce_pf<<<(DH * 64 + 255) / 256, 256, 0, stream>>>(partials, pf);
  k_hidden<<<(BSZ * D_CLS) / 256, 256, 0, stream>>>(pf, We1, be1, hiddenT);
  k_init_out<<<(BSZ * N_ENT / 4 + 255) / 256, 256, 0, stream>>>(be2, out);
  dim3 fgrid((N_ENT + 255) / 256, KF_SPLIT);
  k_final<<<fgrid, 256, 0, stream>>>(hiddenT, We2, out);
}